// Round 2
// baseline (78043.378 us; speedup 1.0000x reference)
//
#include <hip/hip_runtime.h>

#define DIM   512
#define QKVW  1536
#define MLPD  2048
#define NB    256
#define NT    256
#define NLAY  4

typedef __attribute__((ext_vector_type(8))) short short8;
typedef __attribute__((ext_vector_type(4))) float floatx4;

static __device__ __forceinline__ float b2f(unsigned short x){
    return __uint_as_float(((unsigned int)x) << 16);
}
static __device__ __forceinline__ unsigned short f2b(float f){
    unsigned int u = __float_as_uint(f);
    u += 0x7fffu + ((u >> 16) & 1u);
    return (unsigned short)(u >> 16);
}

// ---------------- one-time weight transpose+cast: src f32[K][N] -> dst bf16[N][K] ----------------
__global__ __launch_bounds__(256) void k_transpose(const float* __restrict__ src,
        unsigned short* __restrict__ dst, int K, int N){
    __shared__ unsigned short tile[64][65];
    int r0 = blockIdx.x * 64, c0 = blockIdx.y * 64;
    int tx = threadIdx.x & 63, ty = threadIdx.x >> 6;
    #pragma unroll
    for (int i = 0; i < 16; ++i){
        int r = ty + 4 * i;
        tile[r][tx] = f2b(src[(size_t)(r0 + r) * N + c0 + tx]);
    }
    __syncthreads();
    #pragma unroll
    for (int i = 0; i < 16; ++i){
        int r = ty + 4 * i;
        dst[(size_t)(c0 + r) * K + r0 + tx] = tile[tx][r];
    }
}

// ---------------- shared GEMM building blocks ----------------
// stage a 64x64 bf16 chunk (rows x k) from global (row stride rstride) into lds[64][72]
static __device__ __forceinline__ void stage64(const unsigned short* __restrict__ g,
        int rstride, unsigned short* lds){
    int r = threadIdx.x >> 2, s = threadIdx.x & 3;
    const int4* src = (const int4*)(g + (size_t)r * rstride + s * 16);
    int4* dst = (int4*)(lds + r * 72 + s * 16);
    dst[0] = src[0];
    dst[1] = src[1];
}

// one 64-wide K chunk of MFMA: wave (wm,wn) owns a 32x32 quadrant as 2x2 16x16 frags
static __device__ __forceinline__ void mma_chunk(const unsigned short* __restrict__ A_s, int astride,
        const unsigned short* __restrict__ B_s, floatx4 acc[2][2], int wm, int wn, int lm, int lq){
    #pragma unroll
    for (int ks = 0; ks < 2; ++ks){
        short8 a0 = *(const short8*)(A_s + (wm*32 + lm) * astride + ks*32 + lq*8);
        short8 a1 = *(const short8*)(A_s + (wm*32 + 16 + lm) * astride + ks*32 + lq*8);
        short8 b0 = *(const short8*)(B_s + (wn*32 + lm) * 72 + ks*32 + lq*8);
        short8 b1 = *(const short8*)(B_s + (wn*32 + 16 + lm) * 72 + ks*32 + lq*8);
        acc[0][0] = __builtin_amdgcn_mfma_f32_16x16x32_bf16(a0, b0, acc[0][0], 0, 0, 0);
        acc[0][1] = __builtin_amdgcn_mfma_f32_16x16x32_bf16(a0, b1, acc[0][1], 0, 0, 0);
        acc[1][0] = __builtin_amdgcn_mfma_f32_16x16x32_bf16(a1, b0, acc[1][0], 0, 0, 0);
        acc[1][1] = __builtin_amdgcn_mfma_f32_16x16x32_bf16(a1, b1, acc[1][1], 0, 0, 0);
    }
}

// per-row LayerNorm stats over 64 rows of seq (f32, row width DIM)
static __device__ __forceinline__ void ln_stats(const float* __restrict__ seq, int row0,
        float* mu_s, float* rs_s, float* red){
    int r = threadIdx.x >> 2, p = threadIdx.x & 3;
    const float* s = seq + (size_t)(row0 + r) * DIM + p * 128;
    float sm = 0.f, ss = 0.f;
    for (int k = 0; k < 128; k += 4){
        float4 v = *(const float4*)(s + k);
        sm += v.x + v.y + v.z + v.w;
        ss += v.x*v.x + v.y*v.y + v.z*v.z + v.w*v.w;
    }
    red[r*8 + p] = sm;
    red[r*8 + 4 + p] = ss;
    __syncthreads();
    if (threadIdx.x < 64){
        int rr = threadIdx.x;
        float s4 = red[rr*8+0] + red[rr*8+1] + red[rr*8+2] + red[rr*8+3];
        float q4 = red[rr*8+4] + red[rr*8+5] + red[rr*8+6] + red[rr*8+7];
        float mu = s4 * (1.f / DIM);
        float var = q4 * (1.f / DIM) - mu * mu;
        mu_s[rr] = mu;
        rs_s[rr] = rsqrtf(var + 1e-6f);
    }
    __syncthreads();
}

// stage a 64x64 A chunk with LayerNorm applied on the fly (seq f32 -> bf16 lds)
static __device__ __forceinline__ void stageA_ln(const float* __restrict__ seq, int row0, int kk,
        const float* __restrict__ lns, const float* __restrict__ lnb,
        const float* mu_s, const float* rs_s, unsigned short* lds){
    int r = threadIdx.x >> 2, s = threadIdx.x & 3;
    const float* src = seq + (size_t)(row0 + r) * DIM + kk + s * 16;
    float mu = mu_s[r], rs = rs_s[r];
    unsigned short tmp[16];
    #pragma unroll
    for (int j = 0; j < 16; ++j){
        float g = lns[kk + s*16 + j];
        float bb = lnb[kk + s*16 + j];
        tmp[j] = f2b((src[j] - mu) * rs * g + bb);
    }
    int4* dst = (int4*)(lds + r * 72 + s * 16);
    dst[0] = *(int4*)(tmp);
    dst[1] = *(int4*)(tmp + 8);
}

// ---------------- phase kernels ----------------

// mem gating + mem_tok = mem @ mem_kernel ; builds seq_cur (both token rows); emits out[t-1]
__global__ __launch_bounds__(256) void k_memgemm(int t,
        const float* __restrict__ obs,              // + t*NB*DIM (f32)
        const int* __restrict__ dones,              // + t*NB
        const float* __restrict__ mem0,             // initial memory (f32), used at t==0
        const float* __restrict__ seqprev,
        const unsigned short* __restrict__ wT,      // memkT bf16 [512][512]
        float* __restrict__ seqcur,
        float* __restrict__ outprev){               // d_out + (t-1)*NB*DIM (valid if t>0)
    __shared__ unsigned short A_s[64*72];
    __shared__ unsigned short B_s[64*72];
    int n0 = blockIdx.x * 64;   // output col
    int m0 = blockIdx.y * 64;   // batch rows (b)
    int wave = threadIdx.x >> 6, lane = threadIdx.x & 63;
    int wm = wave >> 1, wn = wave & 1, lm = lane & 15, lq = lane >> 4;
    floatx4 z = {0.f, 0.f, 0.f, 0.f};
    floatx4 acc[2][2] = {{z, z}, {z, z}};

    for (int kk = 0; kk < DIM; kk += 64){
        __syncthreads();
        {   // stage gated mem as A (f32 -> bf16)
            int r = threadIdx.x >> 2, s = threadIdx.x & 3;
            int b = m0 + r;
            int done = dones[b];
            unsigned short tmp[16];
            if (t == 0){
                const float* src = mem0 + (size_t)b * DIM + kk + s * 16;
                #pragma unroll
                for (int j = 0; j < 16; ++j) tmp[j] = done ? (unsigned short)0 : f2b(src[j]);
            } else {
                const float* src = seqprev + (size_t)(2*b + 1) * DIM + kk + s * 16;
                #pragma unroll
                for (int j = 0; j < 16; ++j){
                    float x = src[j];
                    if (blockIdx.x == 0) outprev[(size_t)b * DIM + kk + s*16 + j] = x;
                    tmp[j] = done ? (unsigned short)0 : f2b(x);
                }
            }
            int4* dst = (int4*)(A_s + r * 72 + s * 16);
            dst[0] = *(int4*)tmp;
            dst[1] = *(int4*)(tmp + 8);
        }
        stage64(wT + (size_t)n0 * DIM + kk, DIM, B_s);
        __syncthreads();
        mma_chunk(A_s, 72, B_s, acc, wm, wn, lm, lq);
    }
    #pragma unroll
    for (int fm = 0; fm < 2; ++fm)
    #pragma unroll
    for (int fn = 0; fn < 2; ++fn)
    #pragma unroll
    for (int i = 0; i < 4; ++i){
        int b = m0 + wm*32 + fm*16 + lq*4 + i;
        int c = n0 + wn*32 + fn*16 + lm;
        seqcur[(size_t)(2*b) * DIM + c] = acc[fm][fn][i];                   // mem token
        seqcur[(size_t)(2*b + 1) * DIM + c] = obs[(size_t)b * DIM + c];     // obs token
    }
}

// LN1 + fused QKV GEMM (+bias) -> qkv bf16 [512][1536]
__global__ __launch_bounds__(256) void k_qkv(const float* __restrict__ seq,
        const unsigned short* __restrict__ wT,      // qkvT for this layer [1536][512]
        const float* __restrict__ bq, const float* __restrict__ bk,
        const float* __restrict__ bv,
        const float* __restrict__ lns, const float* __restrict__ lnb,
        unsigned short* __restrict__ qkv){
    __shared__ unsigned short A_s[64*72];
    __shared__ unsigned short B_s[64*72];
    __shared__ float red[64*8];
    __shared__ float mu_s[64], rs_s[64];
    int n0 = blockIdx.x * 64;   // 0..1535
    int m0 = blockIdx.y * 64;   // token rows
    ln_stats(seq, m0, mu_s, rs_s, red);
    int wave = threadIdx.x >> 6, lane = threadIdx.x & 63;
    int wm = wave >> 1, wn = wave & 1, lm = lane & 15, lq = lane >> 4;
    floatx4 z = {0.f, 0.f, 0.f, 0.f};
    floatx4 acc[2][2] = {{z, z}, {z, z}};
    for (int kk = 0; kk < DIM; kk += 64){
        __syncthreads();
        stageA_ln(seq, m0, kk, lns, lnb, mu_s, rs_s, A_s);
        stage64(wT + (size_t)n0 * DIM + kk, DIM, B_s);
        __syncthreads();
        mma_chunk(A_s, 72, B_s, acc, wm, wn, lm, lq);
    }
    int sec = n0 >> 9;
    const float* bias = (sec == 0) ? bq : ((sec == 1) ? bk : bv);
    int nsec = n0 & 511;
    #pragma unroll
    for (int fm = 0; fm < 2; ++fm)
    #pragma unroll
    for (int fn = 0; fn < 2; ++fn)
    #pragma unroll
    for (int i = 0; i < 4; ++i){
        int row = m0 + wm*32 + fm*16 + lq*4 + i;
        int cl = wn*32 + fn*16 + lm;
        float v = acc[fm][fn][i] + bias[nsec + cl];
        qkv[(size_t)row * QKVW + n0 + cl] = f2b(v);
    }
}

// attention (2-token softmax) prologue + O GEMM, atomicAdd residual into seq (f32)
// split over heads: blockIdx.z selects heads [4z, 4z+4) == k range [256z, 256z+256)
__global__ __launch_bounds__(256) void k_attno(const unsigned short* __restrict__ qkv,
        const unsigned short* __restrict__ wT,      // woT for this layer [512][512]
        const float* __restrict__ bo,
        float* __restrict__ seq){
    __shared__ unsigned short O_s[64*264];
    __shared__ unsigned short B_s[64*72];
    int n0 = blockIdx.x * 64;
    int m0 = blockIdx.y * 64;
    int sp = blockIdx.z;        // 0..1
    if (threadIdx.x < 128){
        int b_l = threadIdx.x >> 2, h_l = threadIdx.x & 3;
        int h = sp * 4 + h_l;
        const unsigned short* q0 = qkv + (size_t)(m0 + 2*b_l) * QKVW + h * 64;
        const unsigned short* q1 = q0 + QKVW;
        const unsigned short* k0p = q0 + 512;
        const unsigned short* k1p = k0p + QKVW;
        const unsigned short* v0p = q0 + 1024;
        const unsigned short* v1p = v0p + QKVW;
        float s00 = 0, s01 = 0, s10 = 0, s11 = 0;
        for (int f8 = 0; f8 < 8; ++f8){
            short8 a0 = *(const short8*)(q0 + f8*8);
            short8 a1 = *(const short8*)(q1 + f8*8);
            short8 c0 = *(const short8*)(k0p + f8*8);
            short8 c1 = *(const short8*)(k1p + f8*8);
            #pragma unroll
            for (int j = 0; j < 8; ++j){
                float qa = b2f((unsigned short)a0[j]);
                float qb = b2f((unsigned short)a1[j]);
                float ka = b2f((unsigned short)c0[j]);
                float kb = b2f((unsigned short)c1[j]);
                s00 += qa*ka; s01 += qa*kb; s10 += qb*ka; s11 += qb*kb;
            }
        }
        s00 *= 0.125f; s01 *= 0.125f; s10 *= 0.125f; s11 *= 0.125f;
        float m0v = fmaxf(s00, s01), m1v = fmaxf(s10, s11);
        float e00 = __expf(s00 - m0v), e01 = __expf(s01 - m0v);
        float e10 = __expf(s10 - m1v), e11 = __expf(s11 - m1v);
        float i0 = 1.f / (e00 + e01), i1 = 1.f / (e10 + e11);
        float p00 = e00*i0, p01 = e01*i0, p10 = e10*i1, p11 = e11*i1;
        for (int f8 = 0; f8 < 8; ++f8){
            short8 va = *(const short8*)(v0p + f8*8);
            short8 vb = *(const short8*)(v1p + f8*8);
            unsigned short o0[8], o1[8];
            #pragma unroll
            for (int j = 0; j < 8; ++j){
                float x0 = b2f((unsigned short)va[j]);
                float x1 = b2f((unsigned short)vb[j]);
                o0[j] = f2b(p00*x0 + p01*x1);
                o1[j] = f2b(p10*x0 + p11*x1);
            }
            *(int4*)(O_s + (2*b_l) * 264 + h_l*64 + f8*8) = *(int4*)o0;
            *(int4*)(O_s + (2*b_l + 1) * 264 + h_l*64 + f8*8) = *(int4*)o1;
        }
    }
    int wave = threadIdx.x >> 6, lane = threadIdx.x & 63;
    int wm = wave >> 1, wn = wave & 1, lm = lane & 15, lq = lane >> 4;
    floatx4 z = {0.f, 0.f, 0.f, 0.f};
    floatx4 acc[2][2] = {{z, z}, {z, z}};
    for (int c = 0; c < 4; ++c){
        int kkg = sp * 256 + c * 64;
        __syncthreads();
        stage64(wT + (size_t)n0 * DIM + kkg, DIM, B_s);
        __syncthreads();
        mma_chunk(O_s + c * 64, 264, B_s, acc, wm, wn, lm, lq);
    }
    #pragma unroll
    for (int fm = 0; fm < 2; ++fm)
    #pragma unroll
    for (int fn = 0; fn < 2; ++fn)
    #pragma unroll
    for (int i = 0; i < 4; ++i){
        int row = m0 + wm*32 + fm*16 + lq*4 + i;
        int cc = n0 + wn*32 + fn*16 + lm;
        float v = acc[fm][fn][i];
        if (sp == 0) v += bo[cc];
        atomicAdd(&seq[(size_t)row * DIM + cc], v);
    }
}

// LN2 + MLP1 GEMM + bias + gelu(tanh) -> h1 bf16 [512][2048]
__global__ __launch_bounds__(256) void k_mlp1(const float* __restrict__ seq,
        const unsigned short* __restrict__ wT,      // w1T for this layer [2048][512]
        const float* __restrict__ b1,
        const float* __restrict__ lns, const float* __restrict__ lnb,
        unsigned short* __restrict__ h1){
    __shared__ unsigned short A_s[64*72];
    __shared__ unsigned short B_s[64*72];
    __shared__ float red[64*8];
    __shared__ float mu_s[64], rs_s[64];
    int n0 = blockIdx.x * 64;   // 0..2047
    int m0 = blockIdx.y * 64;
    ln_stats(seq, m0, mu_s, rs_s, red);
    int wave = threadIdx.x >> 6, lane = threadIdx.x & 63;
    int wm = wave >> 1, wn = wave & 1, lm = lane & 15, lq = lane >> 4;
    floatx4 z = {0.f, 0.f, 0.f, 0.f};
    floatx4 acc[2][2] = {{z, z}, {z, z}};
    for (int kk = 0; kk < DIM; kk += 64){
        __syncthreads();
        stageA_ln(seq, m0, kk, lns, lnb, mu_s, rs_s, A_s);
        stage64(wT + (size_t)n0 * DIM + kk, DIM, B_s);
        __syncthreads();
        mma_chunk(A_s, 72, B_s, acc, wm, wn, lm, lq);
    }
    #pragma unroll
    for (int fm = 0; fm < 2; ++fm)
    #pragma unroll
    for (int fn = 0; fn < 2; ++fn)
    #pragma unroll
    for (int i = 0; i < 4; ++i){
        int row = m0 + wm*32 + fm*16 + lq*4 + i;
        int cc = n0 + wn*32 + fn*16 + lm;
        float v = acc[fm][fn][i] + b1[cc];
        float g = 0.5f * v * (1.f + tanhf(0.7978845608028654f * (v + 0.044715f * v * v * v)));
        h1[(size_t)row * MLPD + cc] = f2b(g);
    }
}

// MLP2 GEMM (K=2048, split 4) + bias, atomicAdd residual into seq
__global__ __launch_bounds__(256) void k_mlp2(const unsigned short* __restrict__ h1,
        const unsigned short* __restrict__ wT,      // w2T for this layer [512][2048]
        const float* __restrict__ b2,
        float* __restrict__ seq){
    __shared__ unsigned short A_s[64*72];
    __shared__ unsigned short B_s[64*72];
    int n0 = blockIdx.x * 64;
    int m0 = blockIdx.y * 64;
    int sp = blockIdx.z;        // 0..3
    int wave = threadIdx.x >> 6, lane = threadIdx.x & 63;
    int wm = wave >> 1, wn = wave & 1, lm = lane & 15, lq = lane >> 4;
    floatx4 z = {0.f, 0.f, 0.f, 0.f};
    floatx4 acc[2][2] = {{z, z}, {z, z}};
    for (int c = 0; c < 8; ++c){
        int kk = sp * 512 + c * 64;
        __syncthreads();
        stage64(h1 + (size_t)m0 * MLPD + kk, MLPD, A_s);
        stage64(wT + (size_t)n0 * MLPD + kk, MLPD, B_s);
        __syncthreads();
        mma_chunk(A_s, 72, B_s, acc, wm, wn, lm, lq);
    }
    #pragma unroll
    for (int fm = 0; fm < 2; ++fm)
    #pragma unroll
    for (int fn = 0; fn < 2; ++fn)
    #pragma unroll
    for (int i = 0; i < 4; ++i){
        int row = m0 + wm*32 + fm*16 + lq*4 + i;
        int cc = n0 + wn*32 + fn*16 + lm;
        float v = acc[fm][fn][i];
        if (sp == 0) v += b2[cc];
        atomicAdd(&seq[(size_t)row * DIM + cc], v);
    }
}

// write out[T-1] from the final seq buffer
__global__ __launch_bounds__(256) void k_flush(const float* __restrict__ seq,
        float* __restrict__ out){
    int idx = blockIdx.x * 256 + threadIdx.x;   // over NB*DIM
    int b = idx >> 9, c = idx & 511;
    out[idx] = seq[(size_t)(2*b + 1) * DIM + c];
}

// ---------------- host launch ----------------
extern "C" void kernel_launch(void* const* d_in, const int* in_sizes, int n_in,
                              void* d_out, int out_size, void* d_ws, size_t ws_size,
                              hipStream_t stream){
    const float* obs  = (const float*)d_in[0];
    const int*   dones= (const int*)d_in[1];
    const float* mem0 = (const float*)d_in[2];
    const float* memk = (const float*)d_in[3];
    const float* ln1s = (const float*)d_in[4];
    const float* ln1b = (const float*)d_in[5];
    const float* wq   = (const float*)d_in[6];
    const float* bq   = (const float*)d_in[7];
    const float* wk   = (const float*)d_in[8];
    const float* bk   = (const float*)d_in[9];
    const float* wv   = (const float*)d_in[10];
    const float* bv   = (const float*)d_in[11];
    const float* wo   = (const float*)d_in[12];
    const float* bo   = (const float*)d_in[13];
    const float* ln2s = (const float*)d_in[14];
    const float* ln2b = (const float*)d_in[15];
    const float* w1   = (const float*)d_in[16];
    const float* b1   = (const float*)d_in[17];
    const float* w2   = (const float*)d_in[18];
    const float* b2   = (const float*)d_in[19];
    float* out = (float*)d_out;

    char* ws = (char*)d_ws;
    unsigned short* memkT = (unsigned short*)(ws + 0);          // 512*512 bf16
    unsigned short* qkvT  = (unsigned short*)(ws + 524288);     // 4*1536*512
    unsigned short* woT   = (unsigned short*)(ws + 6815744);    // 4*512*512
    unsigned short* w1T   = (unsigned short*)(ws + 8912896);    // 4*2048*512
    unsigned short* w2T   = (unsigned short*)(ws + 17301504);   // 4*512*2048
    float* seq0           = (float*)(ws + 25690112);            // 512*512 f32
    float* seq1           = (float*)(ws + 26738688);            // 512*512 f32
    unsigned short* qkv   = (unsigned short*)(ws + 27787264);   // 512*1536 bf16
    unsigned short* h1    = (unsigned short*)(ws + 29360128);   // 512*2048 bf16
    // total 31457280 bytes

    dim3 blk(256);
    k_transpose<<<dim3(8, 8), blk, 0, stream>>>(memk, memkT, 512, 512);
    for (int l = 0; l < NLAY; ++l){
        k_transpose<<<dim3(8, 8), blk, 0, stream>>>(wq + (size_t)l*262144, qkvT + (size_t)l*786432,          512, 512);
        k_transpose<<<dim3(8, 8), blk, 0, stream>>>(wk + (size_t)l*262144, qkvT + (size_t)l*786432 + 262144, 512, 512);
        k_transpose<<<dim3(8, 8), blk, 0, stream>>>(wv + (size_t)l*262144, qkvT + (size_t)l*786432 + 524288, 512, 512);
        k_transpose<<<dim3(8, 8), blk, 0, stream>>>(wo + (size_t)l*262144, woT + (size_t)l*262144,           512, 512);
        k_transpose<<<dim3(8, 32), blk, 0, stream>>>(w1 + (size_t)l*1048576, w1T + (size_t)l*1048576,        512, 2048);
        k_transpose<<<dim3(32, 8), blk, 0, stream>>>(w2 + (size_t)l*1048576, w2T + (size_t)l*1048576,        2048, 512);
    }

    for (int t = 0; t < NT; ++t){
        float* scur  = (t & 1) ? seq1 : seq0;
        float* sprev = (t & 1) ? seq0 : seq1;
        k_memgemm<<<dim3(8, 4), blk, 0, stream>>>(t,
                obs + (size_t)t * NB * DIM, dones + t * NB, mem0,
                sprev, memkT, scur,
                out + (size_t)(t > 0 ? t - 1 : 0) * NB * DIM);
        for (int l = 0; l < NLAY; ++l){
            k_qkv<<<dim3(24, 8), blk, 0, stream>>>(scur, qkvT + (size_t)l*786432,
                    bq + l*512, bk + l*512, bv + l*512, ln1s + l*512, ln1b + l*512, qkv);
            k_attno<<<dim3(8, 8, 2), blk, 0, stream>>>(qkv, woT + (size_t)l*262144, bo + l*512, scur);
            k_mlp1<<<dim3(32, 8, 1), blk, 0, stream>>>(scur, w1T + (size_t)l*1048576, b1 + l*2048,
                    ln2s + l*512, ln2b + l*512, h1);
            k_mlp2<<<dim3(8, 8, 4), blk, 0, stream>>>(h1, w2T + (size_t)l*1048576, b2 + l*512, scur);
        }
    }
    k_flush<<<dim3(512), blk, 0, stream>>>(((NT - 1) & 1) ? seq1 : seq0,
            out + (size_t)(NT - 1) * NB * DIM);
}